// Round 1
// baseline (104.585 us; speedup 1.0000x reference)
//
#include <hip/hip_runtime.h>

#define NNODES 1024
#define NHEADS 8
#define NHID 16
#define DIM 128            // NHEADS * NHID
#define NEG_SLOPE 0.2f

// Kernel 1: g = h @ W^T ; src[i,h] = g[i,h,:]·a_src ; dst[i,h] = g[i,h,:]·a_dst
__global__ __launch_bounds__(128) void proj_kernel(
    const float* __restrict__ h, const float* __restrict__ W,
    const float* __restrict__ attn_w,
    float* __restrict__ g, float* __restrict__ srcv, float* __restrict__ dstv)
{
    const int i = blockIdx.x;
    const int o = threadIdx.x;          // 0..127 output feature
    __shared__ float hs[DIM];
    hs[o] = h[(size_t)i * DIM + o];
    __syncthreads();
    const float4* hv = (const float4*)hs;
    const float4* wv = (const float4*)(W + (size_t)o * DIM);
    float acc = 0.f;
#pragma unroll
    for (int k = 0; k < DIM / 4; k++) {
        float4 a = hv[k]; float4 b = wv[k];
        acc = fmaf(a.x, b.x, fmaf(a.y, b.y, fmaf(a.z, b.z, fmaf(a.w, b.w, acc))));
    }
    g[(size_t)i * DIM + o] = acc;
    const int f  = o & (NHID - 1);
    const int hd = o >> 4;
    float sv = acc * attn_w[f];
    float dv = acc * attn_w[NHID + f];
#pragma unroll
    for (int off = 8; off > 0; off >>= 1) {     // reduce within 16-lane head group
        sv += __shfl_xor(sv, off, 64);
        dv += __shfl_xor(dv, off, 64);
    }
    if (f == 0) { srcv[i * NHEADS + hd] = sv; dstv[i * NHEADS + hd] = dv; }
}

// Kernel 2: one block per node i. Fused triple-softmax + weighted aggregation.
__global__ __launch_bounds__(256) void attn_kernel(
    const int* __restrict__ adj, const float* __restrict__ s,
    const float* __restrict__ g, const float* __restrict__ srcv,
    const float* __restrict__ dstv, float* __restrict__ out)
{
    const int i    = blockIdx.x;
    const int tid  = threadIdx.x;       // 0..255
    const int lane = tid & 63;
    const int wid  = tid >> 6;

    __shared__ float stat[9];           // 1/z_e[0..7], 1/z_s
    __shared__ float red[4][9];
    __shared__ float w_lds[256][9];     // [j within tile][head], pad col to 9
    __shared__ float acc_lds[128];
    __shared__ float red_zt[4][8];
    __shared__ float src_sh[8];

    if (tid < 8) src_sh[tid] = srcv[i * NHEADS + tid];
    __syncthreads();
    float sH[8];
#pragma unroll
    for (int hh = 0; hh < 8; hh++) sH[hh] = src_sh[hh];

    const int*   adjrow = adj + (size_t)i * NNODES;
    const float* srow   = s   + (size_t)i * NNODES;
    const float4* dst4  = (const float4*)dstv;

    // ---- Phase A: denominators of softmax(e) per head and softmax(s) ----
    float z[9];
#pragma unroll
    for (int c = 0; c < 9; c++) z[c] = 0.f;
    for (int j = tid; j < NNODES; j += 256) {
        if (adjrow[j] != 0) {
            float4 d0 = dst4[j * 2];
            float4 d1 = dst4[j * 2 + 1];
            float dj[8] = {d0.x, d0.y, d0.z, d0.w, d1.x, d1.y, d1.z, d1.w};
#pragma unroll
            for (int hh = 0; hh < 8; hh++) {
                float e = sH[hh] + dj[hh];
                e = e > 0.f ? e : NEG_SLOPE * e;
                z[hh] += __expf(e);
            }
            z[8] += __expf(srow[j]);
        }
    }
#pragma unroll
    for (int off = 32; off > 0; off >>= 1)
#pragma unroll
        for (int c = 0; c < 9; c++) z[c] += __shfl_xor(z[c], off, 64);
    if (lane == 0)
#pragma unroll
        for (int c = 0; c < 9; c++) red[wid][c] = z[c];
    __syncthreads();
    if (tid < 9) {
        float t = red[0][tid] + red[1][tid] + red[2][tid] + red[3][tid];
        stat[tid] = 1.f / t;
    }
    __syncthreads();
    float iz[8];
#pragma unroll
    for (int hh = 0; hh < 8; hh++) iz[hh] = stat[hh];
    const float izs = stat[8];

    // ---- Phase B: final weights w = exp(a + s') (1 at masked), aggregate ----
    const int half = tid >> 7;          // which 128-j half of the tile
    const int hf   = tid & 127;         // output element h*16+f
    const int oh   = hf >> 4;
    float acc = 0.f;
    float zt[8];
#pragma unroll
    for (int hh = 0; hh < 8; hh++) zt[hh] = 0.f;

    for (int tile = 0; tile < 4; tile++) {
        const int j = tile * 256 + tid;
        float w[8];
        if (adjrow[j] != 0) {
            float sp = __expf(srow[j]) * izs;
            float4 d0 = dst4[j * 2];
            float4 d1 = dst4[j * 2 + 1];
            float dj[8] = {d0.x, d0.y, d0.z, d0.w, d1.x, d1.y, d1.z, d1.w};
#pragma unroll
            for (int hh = 0; hh < 8; hh++) {
                float e = sH[hh] + dj[hh];
                e = e > 0.f ? e : NEG_SLOPE * e;
                float aa = __expf(e) * iz[hh];
                w[hh] = __expf(aa + sp);
            }
        } else {
#pragma unroll
            for (int hh = 0; hh < 8; hh++) w[hh] = 1.0f;   // exp(0)
        }
#pragma unroll
        for (int hh = 0; hh < 8; hh++) {
            w_lds[tid][hh] = w[hh];
            zt[hh] += w[hh];
        }
        __syncthreads();
        const float* gp = g + (size_t)(tile * 256 + half * 128) * DIM + hf;
#pragma unroll 8
        for (int jj = 0; jj < 128; jj++)
            acc = fmaf(w_lds[half * 128 + jj][oh], gp[(size_t)jj * DIM], acc);
        __syncthreads();
    }

    // ---- combine halves, normalize by z_t, write ----
    if (tid >= 128) acc_lds[hf] = acc;
#pragma unroll
    for (int off = 32; off > 0; off >>= 1)
#pragma unroll
        for (int hh = 0; hh < 8; hh++) zt[hh] += __shfl_xor(zt[hh], off, 64);
    if (lane == 0)
#pragma unroll
        for (int hh = 0; hh < 8; hh++) red_zt[wid][hh] = zt[hh];
    __syncthreads();
    if (tid < 128) {
        float zq = red_zt[0][oh] + red_zt[1][oh] + red_zt[2][oh] + red_zt[3][oh];
        out[(size_t)i * DIM + hf] = (acc + acc_lds[hf]) / zq;
    }
}

extern "C" void kernel_launch(void* const* d_in, const int* in_sizes, int n_in,
                              void* d_out, int out_size, void* d_ws, size_t ws_size,
                              hipStream_t stream) {
    const float* h      = (const float*)d_in[0];
    const int*   adj    = (const int*)  d_in[1];
    const float* s      = (const float*)d_in[2];
    const float* W      = (const float*)d_in[3];
    const float* attn_w = (const float*)d_in[4];
    float* out  = (float*)d_out;
    float* g    = (float*)d_ws;                       // 1024*128 floats
    float* srcv = g + (size_t)NNODES * DIM;           // 1024*8
    float* dstv = srcv + (size_t)NNODES * NHEADS;     // 1024*8

    proj_kernel<<<NNODES, DIM, 0, stream>>>(h, W, attn_w, g, srcv, dstv);
    attn_kernel<<<NNODES, 256, 0, stream>>>(adj, s, g, srcv, dstv, out);
}